// Round 5
// baseline (68.562 us; speedup 1.0000x reference)
//
#include <hip/hip_runtime.h>
#include <hip/hip_bf16.h>
#include <stdint.h>

// Problem constants: A=2048 agents, H=128, G=8 (64 cells), NB=32, CELL=8
// pooled = (grid[A,64,128] flattened) @ W.T + b ; out masked by valid_i.

typedef __attribute__((ext_vector_type(4))) float f32x4;
typedef __attribute__((ext_vector_type(8))) short short8;

// workspace layout (bytes)
#define O_HB   0u          // bf16 hidden [2049][128]  (row 2048 = zeros, dummy target)
#define O_WB   1048576u    // bf16 W      [128][8192]
#define O_GRID 3145728u    // bf16 grid   [2048][8192]
#define O_PART 36700160u   // f32 partials [16][2048][128]
// total ~51 MB

__device__ __forceinline__ void gl_lds16(const void* g, void* l) {
  __builtin_amdgcn_global_load_lds((const __attribute__((address_space(1))) void*)g,
                                   (__attribute__((address_space(3))) void*)l, 16, 0, 0);
}

__device__ __forceinline__ float bf_lo(uint32_t w) {
  union { uint32_t u; float f; } v{w << 16}; return v.f;
}
__device__ __forceinline__ float bf_hi(uint32_t w) {
  union { uint32_t u; float f; } v{w & 0xffff0000u}; return v.f;
}
__device__ __forceinline__ uint32_t pack_bf2(float x, float y) {
  __hip_bfloat16 bx = __float2bfloat16(x), by = __float2bfloat16(y);
  return ((uint32_t)(*(unsigned short*)&by) << 16) | (*(unsigned short*)&bx);
}

// ---------------- prep: f32 -> bf16 conversions ----------------
__global__ __launch_bounds__(256) void sp_prep(const float* __restrict__ hidden,
                                               const float* __restrict__ W,
                                               __hip_bfloat16* __restrict__ hb,
                                               __hip_bfloat16* __restrict__ wb) {
  int idx = blockIdx.x * 256 + threadIdx.x;
  const int HID4 = (2049 * 128) / 4;   // 65568 groups of 4
  const int W4   = (128 * 8192) / 4;   // 262144 groups of 4
  if (idx < HID4) {
    int e = idx * 4;
    float4 v = make_float4(0.f, 0.f, 0.f, 0.f);
    if (e < 2048 * 128) v = *reinterpret_cast<const float4*>(hidden + e);
    ushort4 pk;
    pk.x = (ushort)(pack_bf2(v.x, v.x) & 0xffffu);
    pk.y = (ushort)(pack_bf2(v.y, v.y) & 0xffffu);
    pk.z = (ushort)(pack_bf2(v.z, v.z) & 0xffffu);
    pk.w = (ushort)(pack_bf2(v.w, v.w) & 0xffffu);
    *reinterpret_cast<ushort4*>(hb + e) = pk;
  } else if (idx < HID4 + W4) {
    int e = (idx - HID4) * 4;
    float4 v = *reinterpret_cast<const float4*>(W + e);
    ushort4 pk;
    pk.x = (ushort)(pack_bf2(v.x, v.x) & 0xffffu);
    pk.y = (ushort)(pack_bf2(v.y, v.y) & 0xffffu);
    pk.z = (ushort)(pack_bf2(v.z, v.z) & 0xffffu);
    pk.w = (ushort)(pack_bf2(v.w, v.w) & 0xffffu);
    *reinterpret_cast<ushort4*>(wb + e) = pk;
  }
}

// ---------------- build: per-agent counting sort + 2-rows-per-load gather ----------------
// 256 threads (4 waves). Phase A: bin all 2048 j's (bins in VGPRs), per-WAVE LDS
// histograms. Phase B: wave-0 shfl prefix scan over padded cell totals; per-wave
// scatter bases. Phase C: scatter (intra-wave atomics only). Phase D: lane l owns
// dword-pair (l&31) of a row; lanes 0-31 process even list entries, 32-63 odd
// (ds_read_u16 list[k + (l>>5)]); one global_load_dwordx2 moves 2 rows per
// instruction; cross-half combine via shfl_xor(32) at cell end.
__global__ __launch_bounds__(256) void sp_build(const float* __restrict__ pos,
                                                const int* __restrict__ mask,
                                                const __hip_bfloat16* __restrict__ hb,
                                                __hip_bfloat16* __restrict__ grid) {
  __shared__ __align__(8) uint16_t list[2304];   // padded cell-sorted j list (dummy = 2048)
  __shared__ int hist[4][64];                    // per-wave histograms
  __shared__ int cur[4][64];                     // per-wave scatter cursors
  __shared__ int offs[65];
  int t = threadIdx.x;
  int wv = t >> 6;
  int i = blockIdx.x;
  float pxi = pos[2 * i], pyi = pos[2 * i + 1];
  reinterpret_cast<int*>(hist)[t] = 0;
  __syncthreads();
  const float2* pos2 = reinterpret_cast<const float2*>(pos);
  int bins[8];
  #pragma unroll
  for (int jj = 0; jj < 8; ++jj) {
    int j = t + jj * 256;
    float2 pj = pos2[j];
    float rx = pj.x - pxi, ry = pj.y - pyi;
    // NaN rel -> comparisons false -> invalid (matches reference)
    bool ok = (fabsf(rx) < 32.f) && (fabsf(ry) < 32.f) && (j != i) && (mask[j] != 0);
    int b = -1;
    if (ok) {
      // rx,ry in (-32,32): (rx+32)*0.125 in [0,8) exactly as f32; clip is a no-op
      int col = (int)floorf((rx + 32.f) * 0.125f);
      int row = (int)floorf((ry + 32.f) * 0.125f);
      b = row * 8 + col;
      atomicAdd(&hist[wv][b], 1);
    }
    bins[jj] = b;
  }
  // fill list with dummy before scatter (padding slots stay dummy)
  #pragma unroll
  for (int q = 0; q < 9; ++q) {
    int k = t + q * 256;
    if (k < 2304) list[k] = 2048;
  }
  __syncthreads();
  if (t < 64) {  // wave-0: scan over padded totals + per-wave bases
    int h0 = hist[0][t], h1 = hist[1][t], h2 = hist[2][t], h3 = hist[3][t];
    int tot = h0 + h1 + h2 + h3;
    int padded = (tot + 3) & ~3;
    int x = padded;
    #pragma unroll
    for (int d = 1; d < 64; d <<= 1) {
      int y = __shfl_up(x, d);
      if (t >= d) x += y;
    }
    offs[t + 1] = x;          // inclusive -> start of next cell
    int base = x - padded;
    cur[0][t] = base;
    cur[1][t] = base + h0;
    cur[2][t] = base + h0 + h1;
    cur[3][t] = base + h0 + h1 + h2;
    if (t == 0) offs[0] = 0;
  }
  __syncthreads();
  #pragma unroll
  for (int jj = 0; jj < 8; ++jj) {
    int j = t + jj * 256;
    int b = bins[jj];
    if (b >= 0) { int k = atomicAdd(&cur[wv][b], 1); list[k] = (uint16_t)j; }
  }
  __syncthreads();
  // Phase D: lane l -> dword-pair (l&31); wave wv -> cells c%4==wv.
  int l = t & 63;
  int hi5 = l >> 5;           // which list entry of the pair this lane serves
  int lq = l & 31;            // dword-pair index within the 128-col row
  const uint2* hb2 = reinterpret_cast<const uint2*>(hb);  // row j: hb2[j*32 + lq]
  for (int c = wv; c < 64; c += 4) {
    int s0 = offs[c], e0 = offs[c + 1];     // length is a multiple of 4
    float a0 = 0.f, a1 = 0.f, a2 = 0.f, a3 = 0.f;
    float b0 = 0.f, b1 = 0.f, b2 = 0.f, b3 = 0.f;
    for (int k = s0; k + 4 <= e0; k += 4) {
      int jA = (int)list[k + hi5];          // stream A: entries k, k+1
      int jB = (int)list[k + 2 + hi5];      // stream B: entries k+2, k+3
      uint2 wA = hb2[jA * 32 + lq];
      uint2 wB = hb2[jB * 32 + lq];
      a0 += bf_lo(wA.x); a1 += bf_hi(wA.x);
      a2 += bf_lo(wA.y); a3 += bf_hi(wA.y);
      b0 += bf_lo(wB.x); b1 += bf_hi(wB.x);
      b2 += bf_lo(wB.y); b3 += bf_hi(wB.y);
    }
    float c0 = a0 + b0, c1 = a1 + b1, c2 = a2 + b2, c3 = a3 + b3;
    c0 += __shfl_xor(c0, 32);
    c1 += __shfl_xor(c1, 32);
    c2 += __shfl_xor(c2, 32);
    c3 += __shfl_xor(c3, 32);
    if (l < 32) {   // lanes 0-31 write cols [4*lq, 4*lq+4)
      uint2 pk;
      pk.x = pack_bf2(c0, c1);
      pk.y = pack_bf2(c2, c3);
      *reinterpret_cast<uint2*>(
          reinterpret_cast<char*>(grid) + ((size_t)((i << 6) + c) * 256 + (size_t)lq * 8)) = pk;
    }
  }
}

// ---------------- gemm: [2048 x 8192] bf16 @ W[n][k] bf16 -> f32 partials (split-K 16) ----------------
// BM=64, BN=128, BK=64; 4 waves, wave-tile 32x64; mfma_f32_16x16x32_bf16
// LDS rows are 128 B = 8 x 16B granules; XOR-swizzle granule with (row&7):
// stage source pre-swizzled (linear LDS dest, per global_load_lds constraint), read with same XOR.
__global__ __launch_bounds__(256) void sp_gemm(const __hip_bfloat16* __restrict__ Ag,
                                               const __hip_bfloat16* __restrict__ Wb,
                                               float* __restrict__ part) {
  __shared__ __align__(16) char Asm[8192];    // A tile [64][64] bf16
  __shared__ __align__(16) char Bsm[16384];   // B tile [128][64] bf16 (n-major)
  int t = threadIdx.x;
  int lane = t & 63;
  int w = t >> 6;
  int wm = w >> 1, wn = w & 1;
  int bx = blockIdx.x;
  int mt = bx & 31;     // 32 M-tiles of 64 rows
  int sp = bx >> 5;     // 16 K-splits of 512
  int i0 = mt * 64;
  long kbase = (long)sp * 512 * 2;  // byte offset of K-chunk within a row
  const char* Agc = (const char*)Ag;
  const char* Wbc = (const char*)Wb;
  f32x4 acc[2][4] = {};
  for (int st = 0; st < 8; ++st) {   // 8 K-steps of 64
    long kb = kbase + st * 128;
    #pragma unroll
    for (int q = 0; q < 2; ++q) {    // A: 8 KB
      int o = (q * 256 + t) * 16;
      int r = o >> 7;
      int sc = (o & 127) ^ ((r & 7) << 4);
      gl_lds16(Agc + (long)(i0 + r) * 16384 + kb + sc, Asm + o);
    }
    #pragma unroll
    for (int q = 0; q < 4; ++q) {    // B: 16 KB
      int o = (q * 256 + t) * 16;
      int r = o >> 7;
      int sc = (o & 127) ^ ((r & 7) << 4);
      gl_lds16(Wbc + (long)r * 16384 + kb + sc, Bsm + o);
    }
    __syncthreads();
    short8 af[2][2], bfr[4][2];
    #pragma unroll
    for (int fr = 0; fr < 2; ++fr)
      #pragma unroll
      for (int ks = 0; ks < 2; ++ks) {
        int r = wm * 32 + fr * 16 + (lane & 15);
        int g = ks * 4 + (lane >> 4);
        int byt = r * 128 + ((g ^ (r & 7)) << 4);
        af[fr][ks] = *reinterpret_cast<const short8*>(Asm + byt);
      }
    #pragma unroll
    for (int fc = 0; fc < 4; ++fc)
      #pragma unroll
      for (int ks = 0; ks < 2; ++ks) {
        int n = wn * 64 + fc * 16 + (lane & 15);
        int g = ks * 4 + (lane >> 4);
        int byt = n * 128 + ((g ^ (n & 7)) << 4);
        bfr[fc][ks] = *reinterpret_cast<const short8*>(Bsm + byt);
      }
    #pragma unroll
    for (int fr = 0; fr < 2; ++fr)
      #pragma unroll
      for (int fc = 0; fc < 4; ++fc)
        #pragma unroll
        for (int ks = 0; ks < 2; ++ks)
          acc[fr][fc] = __builtin_amdgcn_mfma_f32_16x16x32_bf16(af[fr][ks], bfr[fc][ks],
                                                                acc[fr][fc], 0, 0, 0);
    __syncthreads();
  }
  float* p = part + (long)sp * 262144;
  #pragma unroll
  for (int fr = 0; fr < 2; ++fr)
    #pragma unroll
    for (int fc = 0; fc < 4; ++fc)
      #pragma unroll
      for (int r4 = 0; r4 < 4; ++r4) {
        int ii = i0 + wm * 32 + fr * 16 + (lane >> 4) * 4 + r4;  // C/D: row=(lane>>4)*4+reg
        int nn = wn * 64 + fc * 16 + (lane & 15);                 // C/D: col=lane&15
        p[(long)ii * 128 + nn] = acc[fr][fc][r4];
      }
}

// ---------------- reduce: sum 16 partials + bias, apply valid_i mask ----------------
__global__ __launch_bounds__(256) void sp_reduce(const float* __restrict__ part,
                                                 const float* __restrict__ bias,
                                                 const float* __restrict__ pos,
                                                 const int* __restrict__ mask,
                                                 float* __restrict__ out) {
  int g = blockIdx.x * 256 + threadIdx.x;  // 0..262143
  int i = g >> 7, n = g & 127;
  float acc = bias[n];
  #pragma unroll
  for (int s = 0; s < 16; ++s) acc += part[(long)s * 262144 + g];
  float px = pos[2 * i], py = pos[2 * i + 1];
  bool vi = (mask[i] != 0) && (px == px) && (py == py);  // mask & ~isnan(pos).any
  out[g] = vi ? acc : 0.f;
}

extern "C" void kernel_launch(void* const* d_in, const int* in_sizes, int n_in,
                              void* d_out, int out_size, void* d_ws, size_t ws_size,
                              hipStream_t stream) {
  const float* hidden  = (const float*)d_in[0];
  const float* pos     = (const float*)d_in[1];
  const int*   mask    = (const int*)d_in[2];   // bool input -> int32 per harness contract
  const float* W       = (const float*)d_in[3];
  const float* bias    = (const float*)d_in[4];
  char* ws = (char*)d_ws;
  __hip_bfloat16* hb   = (__hip_bfloat16*)(ws + O_HB);
  __hip_bfloat16* wb   = (__hip_bfloat16*)(ws + O_WB);
  __hip_bfloat16* grid = (__hip_bfloat16*)(ws + O_GRID);
  float* part          = (float*)(ws + O_PART);
  float* out           = (float*)d_out;

  sp_prep<<<1281, 256, 0, stream>>>(hidden, W, hb, wb);
  sp_build<<<2048, 256, 0, stream>>>(pos, mask, hb, grid);
  sp_gemm<<<512, 256, 0, stream>>>(grid, wb, part);
  sp_reduce<<<1024, 256, 0, stream>>>(part, bias, pos, mask, out);
}

// Round 6
// 67.652 us; speedup vs baseline: 1.0134x; 1.0134x over previous
//
#include <hip/hip_runtime.h>
#include <hip/hip_bf16.h>
#include <stdint.h>

// Problem constants: A=2048 agents, H=128, G=8 (64 cells), NB=32, CELL=8
// pooled = (grid[A,64,128] flattened) @ W.T + b ; out masked by valid_i.

typedef __attribute__((ext_vector_type(4))) float f32x4;
typedef __attribute__((ext_vector_type(8))) short short8;

// workspace layout (bytes)
#define O_HB   0u          // bf16 hidden [2049][128]  (row 2048 = zeros, dummy target)
#define O_WB   1048576u    // bf16 W      [128][8192]
#define O_GRID 3145728u    // bf16 grid   [2048][8192]
#define O_PART 36700160u   // f32 partials [16][2048][128]
#define O_POSM 36700160u   // float2 posm[2048] (16KB) -- overlaps part: written by prep,
                           // read by build, then gemm overwrites. Deterministic per launch.
// total ~51 MB

__device__ __forceinline__ void gl_lds16(const void* g, void* l) {
  __builtin_amdgcn_global_load_lds((const __attribute__((address_space(1))) void*)g,
                                   (__attribute__((address_space(3))) void*)l, 16, 0, 0);
}

__device__ __forceinline__ float bf_lo(uint32_t w) {
  union { uint32_t u; float f; } v{w << 16}; return v.f;
}
__device__ __forceinline__ float bf_hi(uint32_t w) {
  union { uint32_t u; float f; } v{w & 0xffff0000u}; return v.f;
}
__device__ __forceinline__ uint32_t pack_bf2(float x, float y) {
  __hip_bfloat16 bx = __float2bfloat16(x), by = __float2bfloat16(y);
  return ((uint32_t)(*(unsigned short*)&by) << 16) | (*(unsigned short*)&bx);
}

// ---------------- prep: f32 -> bf16 conversions + NaN-poisoned posm ----------------
__global__ __launch_bounds__(256) void sp_prep(const float* __restrict__ hidden,
                                               const float* __restrict__ W,
                                               const float* __restrict__ pos,
                                               const int* __restrict__ mask,
                                               __hip_bfloat16* __restrict__ hb,
                                               __hip_bfloat16* __restrict__ wb,
                                               float2* __restrict__ posm) {
  int idx = blockIdx.x * 256 + threadIdx.x;
  const int HID4 = (2049 * 128) / 4;   // 65568 groups of 4
  const int W4   = (128 * 8192) / 4;   // 262144 groups of 4
  if (idx < HID4) {
    int e = idx * 4;
    float4 v = make_float4(0.f, 0.f, 0.f, 0.f);
    if (e < 2048 * 128) v = *reinterpret_cast<const float4*>(hidden + e);
    ushort4 pk;
    pk.x = (ushort)(pack_bf2(v.x, v.x) & 0xffffu);
    pk.y = (ushort)(pack_bf2(v.y, v.y) & 0xffffu);
    pk.z = (ushort)(pack_bf2(v.z, v.z) & 0xffffu);
    pk.w = (ushort)(pack_bf2(v.w, v.w) & 0xffffu);
    *reinterpret_cast<ushort4*>(hb + e) = pk;
  } else if (idx < HID4 + W4) {
    int e = (idx - HID4) * 4;
    float4 v = *reinterpret_cast<const float4*>(W + e);
    ushort4 pk;
    pk.x = (ushort)(pack_bf2(v.x, v.x) & 0xffffu);
    pk.y = (ushort)(pack_bf2(v.y, v.y) & 0xffffu);
    pk.z = (ushort)(pack_bf2(v.z, v.z) & 0xffffu);
    pk.w = (ushort)(pack_bf2(v.w, v.w) & 0xffffu);
    *reinterpret_cast<ushort4*>(wb + e) = pk;
  } else {
    int j = idx - (HID4 + W4);
    if (j < 2048) {
      float2 p = reinterpret_cast<const float2*>(pos)[j];
      union { uint32_t u; float f; } qn{0x7fc00000u};  // quiet NaN
      float2 o;
      bool m = (mask[j] != 0);
      o.x = m ? p.x : qn.f;
      o.y = m ? p.y : qn.f;
      posm[j] = o;
    }
  }
}

// ---------------- build: per-agent counting sort + batched pipelined gather ----------------
// 256 threads (4 waves). Phase A: bin all 2048 j's via NaN-poisoned posm (bins in
// VGPRs), per-WAVE LDS histograms. Phase B: wave-0 shfl prefix scan over cell
// totals padded to x8. Phase C: scatter PRE-MULTIPLIED byte offsets (j<<8),
// intra-wave atomics only. Phase D: per batch of 8 entries, ONE ds_read_b128
// per lane (lanes 0-31 take entries 0-3, lanes 32-63 take 4-7), then 4
// independent dwordx2 gathers; 2-stage pipeline keeps ~8 loads in flight.
// Lane l covers dword-pair (l&31) of each row; cross-half shfl_xor(32) combine.
__global__ __launch_bounds__(256) void sp_build(const float* __restrict__ pos,
                                                const float2* __restrict__ posm,
                                                const __hip_bfloat16* __restrict__ hb,
                                                __hip_bfloat16* __restrict__ grid) {
  __shared__ __align__(16) uint32_t list32[2560];  // cell-sorted j<<8 (dummy = 2048<<8)
  __shared__ int hist[4][64];                      // per-wave histograms
  __shared__ int cur[4][64];                       // per-wave scatter cursors
  __shared__ int offs[65];
  int t = threadIdx.x;
  int wv = t >> 6;
  int i = blockIdx.x;
  float pxi = pos[2 * i], pyi = pos[2 * i + 1];
  reinterpret_cast<int*>(hist)[t] = 0;
  __syncthreads();
  int bins[8];
  #pragma unroll
  for (int jj = 0; jj < 8; ++jj) {
    int j = t + jj * 256;
    float2 pj = posm[j];
    float rx = pj.x - pxi, ry = pj.y - pyi;
    // NaN rel (masked-out j or NaN pos) -> comparisons false -> invalid
    bool ok = (fabsf(rx) < 32.f) && (fabsf(ry) < 32.f) && (j != i);
    int b = -1;
    if (ok) {
      // rx,ry in (-32,32): (rx+32)*0.125 in [0,8) exactly as f32; clip is a no-op
      int col = (int)floorf((rx + 32.f) * 0.125f);
      int row = (int)floorf((ry + 32.f) * 0.125f);
      b = row * 8 + col;
      atomicAdd(&hist[wv][b], 1);
    }
    bins[jj] = b;
  }
  // fill list with dummy before scatter (padding slots stay dummy -> zero row 2048)
  #pragma unroll
  for (int q = 0; q < 10; ++q) {
    int k = t + q * 256;
    if (k < 2560) list32[k] = (2048u << 8);
  }
  __syncthreads();
  if (t < 64) {  // wave-0: scan over x8-padded totals + per-wave scatter bases
    int h0 = hist[0][t], h1 = hist[1][t], h2 = hist[2][t], h3 = hist[3][t];
    int tot = h0 + h1 + h2 + h3;
    int padded = (tot + 7) & ~7;
    int x = padded;
    #pragma unroll
    for (int d = 1; d < 64; d <<= 1) {
      int y = __shfl_up(x, d);
      if (t >= d) x += y;
    }
    offs[t + 1] = x;          // inclusive -> start of next cell
    int base = x - padded;
    cur[0][t] = base;
    cur[1][t] = base + h0;
    cur[2][t] = base + h0 + h1;
    cur[3][t] = base + h0 + h1 + h2;
    if (t == 0) offs[0] = 0;
  }
  __syncthreads();
  #pragma unroll
  for (int jj = 0; jj < 8; ++jj) {
    int j = t + jj * 256;
    int b = bins[jj];
    if (b >= 0) { int k = atomicAdd(&cur[wv][b], 1); list32[k] = ((uint32_t)j << 8); }
  }
  __syncthreads();
  // Phase D
  int l = t & 63;
  int lq = l & 31;
  int dsh = (l >> 5) << 2;            // entry offset within batch: 0 (lanes<32) or 4
  int lqoff = lq * 8;                 // byte offset of this lane's dword-pair in a row
  const char* hbB = reinterpret_cast<const char*>(hb);
  for (int c = wv; c < 64; c += 4) {
    int s0 = offs[c], e0 = offs[c + 1];   // length multiple of 8 (possibly 0)
    float a0 = 0.f, a1 = 0.f, a2 = 0.f, a3 = 0.f;
    float b0 = 0.f, b1 = 0.f, b2 = 0.f, b3 = 0.f;
    if (s0 < e0) {
      uint4 js = *reinterpret_cast<const uint4*>(&list32[s0 + dsh]);
      uint2 r0 = *reinterpret_cast<const uint2*>(hbB + js.x + lqoff);
      uint2 r1 = *reinterpret_cast<const uint2*>(hbB + js.y + lqoff);
      uint2 r2 = *reinterpret_cast<const uint2*>(hbB + js.z + lqoff);
      uint2 r3 = *reinterpret_cast<const uint2*>(hbB + js.w + lqoff);
      for (int k = s0 + 8; k < e0; k += 8) {
        uint4 jn = *reinterpret_cast<const uint4*>(&list32[k + dsh]);
        uint2 n0 = *reinterpret_cast<const uint2*>(hbB + jn.x + lqoff);
        uint2 n1 = *reinterpret_cast<const uint2*>(hbB + jn.y + lqoff);
        uint2 n2 = *reinterpret_cast<const uint2*>(hbB + jn.z + lqoff);
        uint2 n3 = *reinterpret_cast<const uint2*>(hbB + jn.w + lqoff);
        a0 += bf_lo(r0.x); a1 += bf_hi(r0.x); a2 += bf_lo(r0.y); a3 += bf_hi(r0.y);
        b0 += bf_lo(r1.x); b1 += bf_hi(r1.x); b2 += bf_lo(r1.y); b3 += bf_hi(r1.y);
        a0 += bf_lo(r2.x); a1 += bf_hi(r2.x); a2 += bf_lo(r2.y); a3 += bf_hi(r2.y);
        b0 += bf_lo(r3.x); b1 += bf_hi(r3.x); b2 += bf_lo(r3.y); b3 += bf_hi(r3.y);
        r0 = n0; r1 = n1; r2 = n2; r3 = n3;
      }
      a0 += bf_lo(r0.x); a1 += bf_hi(r0.x); a2 += bf_lo(r0.y); a3 += bf_hi(r0.y);
      b0 += bf_lo(r1.x); b1 += bf_hi(r1.x); b2 += bf_lo(r1.y); b3 += bf_hi(r1.y);
      a0 += bf_lo(r2.x); a1 += bf_hi(r2.x); a2 += bf_lo(r2.y); a3 += bf_hi(r2.y);
      b0 += bf_lo(r3.x); b1 += bf_hi(r3.x); b2 += bf_lo(r3.y); b3 += bf_hi(r3.y);
    }
    float c0 = a0 + b0, c1 = a1 + b1, c2 = a2 + b2, c3 = a3 + b3;
    c0 += __shfl_xor(c0, 32);
    c1 += __shfl_xor(c1, 32);
    c2 += __shfl_xor(c2, 32);
    c3 += __shfl_xor(c3, 32);
    if (l < 32) {   // lanes 0-31 write cols [4*lq, 4*lq+4)
      uint2 pk;
      pk.x = pack_bf2(c0, c1);
      pk.y = pack_bf2(c2, c3);
      *reinterpret_cast<uint2*>(
          reinterpret_cast<char*>(grid) + ((size_t)((i << 6) + c) * 256 + (size_t)lq * 8)) = pk;
    }
  }
}

// ---------------- gemm: [2048 x 8192] bf16 @ W[n][k] bf16 -> f32 partials (split-K 16) ----------------
// BM=64, BN=128, BK=64; 4 waves, wave-tile 32x64; mfma_f32_16x16x32_bf16
// LDS rows are 128 B = 8 x 16B granules; XOR-swizzle granule with (row&7):
// stage source pre-swizzled (linear LDS dest, per global_load_lds constraint), read with same XOR.
__global__ __launch_bounds__(256) void sp_gemm(const __hip_bfloat16* __restrict__ Ag,
                                               const __hip_bfloat16* __restrict__ Wb,
                                               float* __restrict__ part) {
  __shared__ __align__(16) char Asm[8192];    // A tile [64][64] bf16
  __shared__ __align__(16) char Bsm[16384];   // B tile [128][64] bf16 (n-major)
  int t = threadIdx.x;
  int lane = t & 63;
  int w = t >> 6;
  int wm = w >> 1, wn = w & 1;
  int bx = blockIdx.x;
  int mt = bx & 31;     // 32 M-tiles of 64 rows
  int sp = bx >> 5;     // 16 K-splits of 512
  int i0 = mt * 64;
  long kbase = (long)sp * 512 * 2;  // byte offset of K-chunk within a row
  const char* Agc = (const char*)Ag;
  const char* Wbc = (const char*)Wb;
  f32x4 acc[2][4] = {};
  for (int st = 0; st < 8; ++st) {   // 8 K-steps of 64
    long kb = kbase + st * 128;
    #pragma unroll
    for (int q = 0; q < 2; ++q) {    // A: 8 KB
      int o = (q * 256 + t) * 16;
      int r = o >> 7;
      int sc = (o & 127) ^ ((r & 7) << 4);
      gl_lds16(Agc + (long)(i0 + r) * 16384 + kb + sc, Asm + o);
    }
    #pragma unroll
    for (int q = 0; q < 4; ++q) {    // B: 16 KB
      int o = (q * 256 + t) * 16;
      int r = o >> 7;
      int sc = (o & 127) ^ ((r & 7) << 4);
      gl_lds16(Wbc + (long)r * 16384 + kb + sc, Bsm + o);
    }
    __syncthreads();
    short8 af[2][2], bfr[4][2];
    #pragma unroll
    for (int fr = 0; fr < 2; ++fr)
      #pragma unroll
      for (int ks = 0; ks < 2; ++ks) {
        int r = wm * 32 + fr * 16 + (lane & 15);
        int g = ks * 4 + (lane >> 4);
        int byt = r * 128 + ((g ^ (r & 7)) << 4);
        af[fr][ks] = *reinterpret_cast<const short8*>(Asm + byt);
      }
    #pragma unroll
    for (int fc = 0; fc < 4; ++fc)
      #pragma unroll
      for (int ks = 0; ks < 2; ++ks) {
        int n = wn * 64 + fc * 16 + (lane & 15);
        int g = ks * 4 + (lane >> 4);
        int byt = n * 128 + ((g ^ (n & 7)) << 4);
        bfr[fc][ks] = *reinterpret_cast<const short8*>(Bsm + byt);
      }
    #pragma unroll
    for (int fr = 0; fr < 2; ++fr)
      #pragma unroll
      for (int fc = 0; fc < 4; ++fc)
        #pragma unroll
        for (int ks = 0; ks < 2; ++ks)
          acc[fr][fc] = __builtin_amdgcn_mfma_f32_16x16x32_bf16(af[fr][ks], bfr[fc][ks],
                                                                acc[fr][fc], 0, 0, 0);
    __syncthreads();
  }
  float* p = part + (long)sp * 262144;
  #pragma unroll
  for (int fr = 0; fr < 2; ++fr)
    #pragma unroll
    for (int fc = 0; fc < 4; ++fc)
      #pragma unroll
      for (int r4 = 0; r4 < 4; ++r4) {
        int ii = i0 + wm * 32 + fr * 16 + (lane >> 4) * 4 + r4;  // C/D: row=(lane>>4)*4+reg
        int nn = wn * 64 + fc * 16 + (lane & 15);                 // C/D: col=lane&15
        p[(long)ii * 128 + nn] = acc[fr][fc][r4];
      }
}

// ---------------- reduce: sum 16 partials + bias, apply valid_i mask ----------------
__global__ __launch_bounds__(256) void sp_reduce(const float* __restrict__ part,
                                                 const float* __restrict__ bias,
                                                 const float* __restrict__ pos,
                                                 const int* __restrict__ mask,
                                                 float* __restrict__ out) {
  int g = blockIdx.x * 256 + threadIdx.x;  // 0..262143
  int i = g >> 7, n = g & 127;
  float acc = bias[n];
  #pragma unroll
  for (int s = 0; s < 16; ++s) acc += part[(long)s * 262144 + g];
  float px = pos[2 * i], py = pos[2 * i + 1];
  bool vi = (mask[i] != 0) && (px == px) && (py == py);  // mask & ~isnan(pos).any
  out[g] = vi ? acc : 0.f;
}

extern "C" void kernel_launch(void* const* d_in, const int* in_sizes, int n_in,
                              void* d_out, int out_size, void* d_ws, size_t ws_size,
                              hipStream_t stream) {
  const float* hidden  = (const float*)d_in[0];
  const float* pos     = (const float*)d_in[1];
  const int*   mask    = (const int*)d_in[2];   // bool input -> int32 per harness contract
  const float* W       = (const float*)d_in[3];
  const float* bias    = (const float*)d_in[4];
  char* ws = (char*)d_ws;
  __hip_bfloat16* hb   = (__hip_bfloat16*)(ws + O_HB);
  __hip_bfloat16* wb   = (__hip_bfloat16*)(ws + O_WB);
  __hip_bfloat16* grid = (__hip_bfloat16*)(ws + O_GRID);
  float* part          = (float*)(ws + O_PART);
  float2* posm         = (float2*)(ws + O_POSM);
  float* out           = (float*)d_out;

  sp_prep<<<1289, 256, 0, stream>>>(hidden, W, pos, mask, hb, wb, posm);
  sp_build<<<2048, 256, 0, stream>>>(pos, posm, hb, grid);
  sp_gemm<<<512, 256, 0, stream>>>(grid, wb, part);
  sp_reduce<<<1024, 256, 0, stream>>>(part, bias, pos, mask, out);
}